// Round 9
// baseline (717.224 us; speedup 1.0000x reference)
//
#include <hip/hip_runtime.h>
#include <math.h>

constexpr int N = 50000;     // nodes
constexpr int E = 100000;    // edges
constexpr int B = 256;       // graphs
constexpr int H = 64;
constexpr int DN = 110;
constexpr int NBLK = (E + 63) / 64;   // 1563 message blocks (exact 64-edge blocks)

#define DEV __device__ __forceinline__

typedef __attribute__((ext_vector_type(8))) short short8;
typedef __attribute__((ext_vector_type(4))) float floatx4;

DEV float sigf(float x) { return 1.0f / (1.0f + expf(-x)); }

// bf16 round-to-nearest-even conversion (manual, header-type-free)
DEV short f2bf(float f) {
    unsigned u = __float_as_uint(f);
    unsigned r = (u + 0x7fffu + ((u >> 16) & 1u)) >> 16;
    return (short)r;
}
DEV float bf2f(short s) { return __uint_as_float(((unsigned)(unsigned short)s) << 16); }

// convert 8 contiguous floats -> hi/lo bf16 fragments
DEV void cvt8(const float* p, short8& hi, short8& lo) {
    float4 u0 = *(const float4*)p;
    float4 u1 = *(const float4*)(p + 4);
    float vv[8] = {u0.x, u0.y, u0.z, u0.w, u1.x, u1.y, u1.z, u1.w};
#pragma unroll
    for (int j = 0; j < 8; ++j) {
        short hb = f2bf(vv[j]);
        hi[j] = hb;
        lo[j] = f2bf(vv[j] - bf2f(hb));
    }
}

// ---------------- generic helpers ----------------
__global__ void k_izero(int* p, int n) {
    int i = blockIdx.x * 256 + threadIdx.x;
    if (i < n) p[i] = 0;
}

// ---------------- fused prep device helpers ----------------
DEV void d_transpose(const float* in, float* out, int R, int C, int idx) {
    int r = idx / C, c = idx % C;
    out[c * R + r] = in[idx];
}

DEV void d_prepB(const float* __restrict__ W, short* __restrict__ out,
                 int NT16, int ld, int trans, int ocap, int kcap, int idx) {
    int lane = idx & 63;
    int t = idx >> 6;
    int ntile = t % NT16;
    int kt = t / NT16;
    int quad = lane >> 4, col = lane & 15;
    int o = ntile * 16 + col;
    short hi[8], lo[8];
#pragma unroll
    for (int j = 0; j < 8; ++j) {
        int k = kt * 32 + quad * 8 + j;
        float v = 0.0f;
        if (o < ocap && k < kcap) v = trans ? W[(size_t)o * ld + k] : W[(size_t)k * ld + o];
        short hb = f2bf(v);
        hi[j] = hb;
        lo[j] = f2bf(v - bf2f(hb));
    }
    short* dh = out + (((size_t)(t * 2 + 0) * 64 + lane) * 8);
    short* dl = out + (((size_t)(t * 2 + 1) * 64 + lane) * 8);
#pragma unroll
    for (int j = 0; j < 8; ++j) { dh[j] = hi[j]; dl[j] = lo[j]; }
}

DEV void d_prepW(const float* __restrict__ bond_W, const float* __restrict__ bond_b,
                 short* __restrict__ wf, int idx) {
    int lane = idx & 63;
    int t = idx >> 6;            // (kk*4+nt)*2+ks
    int ks = t & 1;
    int nt = (t >> 1) & 3;
    int kk = t >> 3;
    const float* S = (kk < 16) ? (bond_W + kk * 4096) : bond_b;
    int quad = lane >> 4, col = lane & 15;
    short hi[8], lo[8];
#pragma unroll
    for (int j = 0; j < 8; ++j) {
        int i = ks * 32 + quad * 8 + j;
        float v = S[i * 64 + nt * 16 + col];
        short hb = f2bf(v);
        hi[j] = hb;
        lo[j] = f2bf(v - bf2f(hb));
    }
    short* dh = wf + (((size_t)(t * 2 + 0) * 64 + lane) * 8);
    short* dl = wf + (((size_t)(t * 2 + 1) * 64 + lane) * 8);
#pragma unroll
    for (int j = 0; j < 8; ++j) { dh[j] = hi[j]; dl[j] = lo[j]; }
}

// fused start-of-graph prep: 4 LSTM transposes + bond prepW + gru/proj prepB
//                            + edge features + graph bounds
__launch_bounds__(256)
__global__ void k_prep0(const float* lWih0, const float* lWhh0, const float* lWih1, const float* lWhh1,
                        float* lW0T, float* lU0T, float* lW1T, float* lU1T,
                        const float* bond_W, const float* bond_b, short* wf,
                        const float* gru_Wih, const float* gru_Whh, short* fgI, short* fgH,
                        const float* proj_W, short* fproj,
                        const float* ea, const float* el, const float* centers,
                        const float* beta, const int* epos, float* ef_t,
                        const int* ng, int* gs, int* ge) {
    int idx = blockIdx.x * 256 + threadIdx.x;
    if (idx < 131072) { d_transpose(lWih0, lW0T, 512, 256, idx); return; }
    idx -= 131072;
    if (idx < 65536) { d_transpose(lWhh0, lU0T, 512, 128, idx); return; }
    idx -= 65536;
    if (idx < 65536) { d_transpose(lWih1, lW1T, 512, 128, idx); return; }
    idx -= 65536;
    if (idx < 65536) { d_transpose(lWhh1, lU1T, 512, 128, idx); return; }
    idx -= 65536;
    if (idx < 8704) { d_prepW(bond_W, bond_b, wf, idx); return; }
    idx -= 8704;
    if (idx < 1536) { d_prepB(gru_Wih, fgI, 12, 64, 1, 192, 64, idx); return; }
    idx -= 1536;
    if (idx < 1536) { d_prepB(gru_Whh, fgH, 12, 64, 1, 192, 64, idx); return; }
    idx -= 1536;
    if (idx < 1024) { d_prepB(proj_W, fproj, 4, 64, 0, 64, DN, idx); return; }
    idx -= 1024;
    if (idx < E) {   // edge features -> ef_t[kk][pos], dst-sorted
        int e = idx;
        int pos = epos[e];
        float L = el[e];
#pragma unroll
        for (int j = 0; j < 8; ++j) ef_t[(size_t)j * E + pos] = ea[e * 8 + j];
#pragma unroll
        for (int j = 0; j < 8; ++j) {
            float d = L - centers[j];
            ef_t[(size_t)(8 + j) * E + pos] = expf(-beta[j] * d * d);
        }
        ef_t[(size_t)16 * E + pos] = 1.0f;
        return;
    }
    idx -= E;
    if (idx < N) {   // graph bounds from sorted node_graph
        int n = idx;
        int g = ng[n];
        int gp = (n == 0) ? -1 : ng[n - 1];
        if (g != gp) {
            gs[g] = n;
            if (n > 0) ge[gp] = n;
            for (int q = gp + 1; q < g; ++q) { gs[q] = 0; ge[q] = 0; }
        }
        if (n == N - 1) {
            ge[g] = N;
            for (int q = g + 1; q < B; ++q) { gs[q] = 0; ge[q] = 0; }
        }
        return;
    }
}
constexpr int PREP0_TOTAL = 131072 + 3 * 65536 + 8704 + 2 * 1536 + 1024 + E + N;

// ---------------- edge sort by dst (counting sort), one-time ----------------
__global__ void k_deg(const int* __restrict__ dst, int* __restrict__ deg) {
    int e = blockIdx.x * 256 + threadIdx.x;
    if (e < E) atomicAdd(&deg[dst[e]], 1);
}
__global__ void k_scan1(const int* __restrict__ deg, int* __restrict__ bsum) {
    __shared__ int s[256];
    int b = blockIdx.x, tid = threadIdx.x;
    int idx = b * 256 + tid;
    s[tid] = (idx < N) ? deg[idx] : 0;
    __syncthreads();
    for (int st = 128; st > 0; st >>= 1) {
        if (tid < st) s[tid] += s[tid + st];
        __syncthreads();
    }
    if (tid == 0) bsum[b] = s[0];
}
__global__ void k_scan2p(int* __restrict__ bsum, int nb) {
    __shared__ int s[256];
    int tid = threadIdx.x;
    int v = (tid < nb) ? bsum[tid] : 0;
    s[tid] = v;
    __syncthreads();
    for (int off = 1; off < 256; off <<= 1) {
        int t = (tid >= off) ? s[tid - off] : 0;
        __syncthreads();
        s[tid] += t;
        __syncthreads();
    }
    if (tid < nb) bsum[tid] = s[tid] - v;   // exclusive
}
__global__ void k_scan3(const int* __restrict__ deg, const int* __restrict__ bsum,
                        int* __restrict__ cursor, int* __restrict__ roff) {
    __shared__ int s[256];
    int b = blockIdx.x, tid = threadIdx.x;
    int idx = b * 256 + tid;
    int v = (idx < N) ? deg[idx] : 0;
    s[tid] = v;
    __syncthreads();
    for (int off = 1; off < 256; off <<= 1) {
        int t = (tid >= off) ? s[tid - off] : 0;
        __syncthreads();
        s[tid] += t;
        __syncthreads();
    }
    if (idx < N) {
        int start = bsum[b] + s[tid] - v;
        cursor[idx] = start;
        roff[idx] = start;
    }
    if (idx == 0) roff[N] = E;
}
__global__ void k_scat(const int* __restrict__ src, const int* __restrict__ dst,
                       int* __restrict__ cursor, int* __restrict__ srcp,
                       int* __restrict__ epos, int* __restrict__ dstp) {
    int e = blockIdx.x * 256 + threadIdx.x;
    if (e >= E) return;
    int d = dst[e];
    int pos = atomicAdd(&cursor[d], 1);
    srcp[pos] = src[e];
    dstp[pos] = d;
    epos[e] = pos;
}

// ---------------- projection via MFMA: v = relu(na @ W + b); x = v (fp32); hs = split(v) ----------------
__launch_bounds__(256)
__global__ void k_projm(const float* __restrict__ na, const short* __restrict__ fp,
                        const float* __restrict__ b, float* __restrict__ x,
                        short* __restrict__ hs) {
    __shared__ float as[16 * 132];   // 16 rows, K padded 110->128 (stride 132 vs bank conflicts)
    int tid = threadIdx.x, lane = tid & 63, nt = tid >> 6;
    int quad = lane >> 4, col = lane & 15;
    int s0 = blockIdx.x * 16;
    for (int i = tid; i < 16 * DN; i += 256) {
        int r = i / DN, c = i % DN;
        as[r * 132 + c] = na[(size_t)s0 * DN + i];
    }
    for (int i = tid; i < 16 * 22; i += 256) {
        int r = i / 22, c = DN + i % 22;
        as[r * 132 + c] = 0.0f;
    }
    __syncthreads();
    const short8* F = (const short8*)fp;
    floatx4 T = {0.0f, 0.0f, 0.0f, 0.0f};
#pragma unroll
    for (int kt = 0; kt < 4; ++kt) {
        const float* ap = as + col * 132 + kt * 32 + quad * 8;
        short8 ah, al;
#pragma unroll
        for (int j = 0; j < 8; ++j) {
            float v = ap[j];
            short hb = f2bf(v);
            ah[j] = hb;
            al[j] = f2bf(v - bf2f(hb));
        }
        int t = kt * 4 + nt;
        short8 bh = F[(t * 2 + 0) * 64 + lane];
        short8 bl = F[(t * 2 + 1) * 64 + lane];
        T = __builtin_amdgcn_mfma_f32_16x16x32_bf16(ah, bh, T, 0, 0, 0);
        T = __builtin_amdgcn_mfma_f32_16x16x32_bf16(al, bh, T, 0, 0, 0);
        T = __builtin_amdgcn_mfma_f32_16x16x32_bf16(ah, bl, T, 0, 0, 0);
    }
    int o = nt * 16 + col;
    float bo = b[o];
#pragma unroll
    for (int r = 0; r < 4; ++r) {
        int n = s0 + quad * 4 + r;
        float v = fmaxf(T[r] + bo, 0.0f);
        x[(size_t)n * 64 + o] = v;
        short hb = f2bf(v);
        hs[(size_t)n * 128 + o] = hb;
        hs[(size_t)n * 128 + 64 + o] = f2bf(v - bf2f(hb));
    }
}

// ---------------- message GEMM + in-block dst aggregation (round-5 structure) ----------------
__launch_bounds__(256)
__global__ void k_msgagg(const short* __restrict__ hs, const float* __restrict__ ef_t,
                         const short* __restrict__ wf, const int* __restrict__ srcp,
                         const int* __restrict__ dstp,
                         float* __restrict__ agg, float* __restrict__ bpart) {
    __shared__ float efs[17 * 64];   // [kk][e_local]
    __shared__ int srcs[64];
    __shared__ int dsh[64];
    __shared__ int shprev;
    __shared__ float Csh[64][68];    // per-edge messages; stride 68 -> 2-way banks (free)

    int tid = threadIdx.x;
    int e0 = blockIdx.x * 64;
    int lane = tid & 63;
    int nt = tid >> 6;
    int quad = lane >> 4, col = lane & 15;

    if (tid < 64) {
        int eg = e0 + tid;
        srcs[tid] = (eg < E) ? srcp[eg] : 0;
        dsh[tid] = (eg < E) ? dstp[eg] : N;   // sentinel N for padded rows
    }
    if (tid == 0) shprev = (e0 == 0) ? -1 : dstp[e0 - 1];
    for (int i = tid; i < 17 * 64; i += 256) {
        int kk = i >> 6, e = i & 63;
        int eg = e0 + e;
        efs[i] = (eg < E) ? ef_t[(size_t)kk * E + eg] : 0.0f;
    }
    __syncthreads();

    // A fragments: direct pre-split loads (hi at +0..63, lo at +64..127 per node row)
    short8 Ah[4][2], Al[4][2];
#pragma unroll
    for (int mt = 0; mt < 4; ++mt) {
        int s = srcs[mt * 16 + col];
        const short* hp = hs + (size_t)s * 128 + quad * 8;
#pragma unroll
        for (int ks = 0; ks < 2; ++ks) {
            Ah[mt][ks] = *(const short8*)(hp + ks * 32);
            Al[mt][ks] = *(const short8*)(hp + 64 + ks * 32);
        }
    }

    const short8* Wf = (const short8*)wf;
    float C[4][4] = {};

#define LOADB(d0, d1, d2, d3, KK)                      \
    {                                                  \
        int tb_ = ((KK) * 4 + nt) * 2;                 \
        d0 = Wf[((tb_ + 0) * 2 + 0) * 64 + lane];      \
        d1 = Wf[((tb_ + 1) * 2 + 0) * 64 + lane];      \
        d2 = Wf[((tb_ + 0) * 2 + 1) * 64 + lane];      \
        d3 = Wf[((tb_ + 1) * 2 + 1) * 64 + lane];      \
    }

    // 3-deep software pipeline: hold kk, kk+1, kk+2; prefetch kk+3 each iteration
    short8 c0, c1, c2, c3, n0_, n1_, n2_, n3_, q0, q1, q2, q3;
    LOADB(c0, c1, c2, c3, 0);
    LOADB(n0_, n1_, n2_, n3_, 1);
    LOADB(q0, q1, q2, q3, 2);

#pragma unroll 1
    for (int kk = 0; kk < 17; ++kk) {
        int kn = kk + 3;
        if (kn > 16) kn = 16;
        short8 p0, p1, p2, p3;
        LOADB(p0, p1, p2, p3, kn);

#pragma unroll
        for (int mt = 0; mt < 4; ++mt) {
            floatx4 T = {0.0f, 0.0f, 0.0f, 0.0f};
            T = __builtin_amdgcn_mfma_f32_16x16x32_bf16(Ah[mt][0], c0, T, 0, 0, 0);
            T = __builtin_amdgcn_mfma_f32_16x16x32_bf16(Ah[mt][1], c1, T, 0, 0, 0);
            T = __builtin_amdgcn_mfma_f32_16x16x32_bf16(Al[mt][0], c0, T, 0, 0, 0);
            T = __builtin_amdgcn_mfma_f32_16x16x32_bf16(Al[mt][1], c1, T, 0, 0, 0);
            T = __builtin_amdgcn_mfma_f32_16x16x32_bf16(Ah[mt][0], c2, T, 0, 0, 0);
            T = __builtin_amdgcn_mfma_f32_16x16x32_bf16(Ah[mt][1], c3, T, 0, 0, 0);
            float4 ef = *(const float4*)&efs[kk * 64 + mt * 16 + quad * 4];
            C[mt][0] += ef.x * T[0];
            C[mt][1] += ef.y * T[1];
            C[mt][2] += ef.z * T[2];
            C[mt][3] += ef.w * T[3];
        }
        c0 = n0_; c1 = n1_; c2 = n2_; c3 = n3_;
        n0_ = q0; n1_ = q1; n2_ = q2; n3_ = q3;
        q0 = p0; q1 = p1; q2 = p2; q3 = p3;
    }
#undef LOADB

    // messages -> LDS (padded rows have efs==0 -> C==0)
#pragma unroll
    for (int mt = 0; mt < 4; ++mt)
#pragma unroll
        for (int r = 0; r < 4; ++r)
            Csh[mt * 16 + quad * 4 + r][nt * 16 + col] = C[mt][r];
    __syncthreads();

    // segmented reduction walk: lane c handles output column c
    if (tid < 64) {
        int c = tid;
        int prevd = shprev;
        int firstd = dsh[0];
        for (int q = prevd + 1; q < firstd; ++q) agg[(size_t)q * 64 + c] = 0.0f;
        int cur = firstd;
        float acc = 0.0f;
        bool owned = (e0 == 0) || (firstd != prevd);
        bool done = false;
        for (int r = 0; r < 64; ++r) {
            int d = dsh[r];
            if (d != cur) {
                if (owned) agg[(size_t)cur * 64 + c] = acc;
                else bpart[(size_t)blockIdx.x * 64 + c] = acc;
                int dc = (d < N) ? d : N;
                for (int q = cur + 1; q < dc; ++q) agg[(size_t)q * 64 + c] = 0.0f;
                cur = d;
                acc = 0.0f;
                owned = true;
                if (cur >= N) { done = true; break; }
            }
            acc += Csh[r][c];
        }
        if (!done) {
            if (owned) agg[(size_t)cur * 64 + c] = acc;
            else bpart[(size_t)blockIdx.x * 64 + c] = acc;
        }
    }
}

// ---------------- GRU step (dense): LDS-staged coalesced I/O + split-bf16 MFMA ----------------
__launch_bounds__(256)
__global__ void k_gru4(const float* agg, const float* __restrict__ bpart,
                       const int* __restrict__ roff, const float* __restrict__ conv_b,
                       short* __restrict__ hs,
                       const short* __restrict__ fI, const short* __restrict__ fH,
                       const float* __restrict__ bih, const float* __restrict__ bhh,
                       float* hf) {
    __shared__ float aggS[32 * 65];   // staged agg rows; reused as hn output buffer
    __shared__ short hsS[32 * 132];   // staged hs rows (hi|lo), stride 132 vs bank conflicts
    int tid = threadIdx.x, lane = tid & 63, nt = tid >> 6;
    int quad = lane >> 4, col = lane & 15;
    int n0 = blockIdx.x * 32;

    // coalesced stage: agg (32x64 f32 = 8KB) and hs (32x128 shorts = 8KB)
    {
        const float* src = agg + (size_t)n0 * 64;
#pragma unroll
        for (int it = 0; it < 2; ++it) {
            int i = tid * 4 + it * 1024;
            float4 v = {0.0f, 0.0f, 0.0f, 0.0f};
            if ((size_t)n0 * 64 + i + 3 < (size_t)N * 64) v = *(const float4*)(src + i);
            int r = i >> 6, c = i & 63;
            *(float4*)&aggS[r * 65 + c] = v;
        }
        const short* hsrc = hs + (size_t)n0 * 128;
#pragma unroll
        for (int it = 0; it < 2; ++it) {
            int i = tid * 8 + it * 2048;
            short8 v = short8{0, 0, 0, 0, 0, 0, 0, 0};
            if ((size_t)n0 * 128 + i + 7 < (size_t)N * 128) v = *(const short8*)(hsrc + i);
            int r = i >> 7, c = i & 127;
            *(short8*)&hsS[r * 132 + c] = v;
        }
    }
    __syncthreads();

    short8 Gh[2][2], Gl[2][2], Hh[2][2], Hl[2][2];
#pragma unroll
    for (int mt = 0; mt < 2; ++mt) {
        int node = n0 + mt * 16 + col;
        bool ok = node < N;
        int row = mt * 16 + col;
        float acc[2][8];
        const float* ag = &aggS[row * 65];
#pragma unroll
        for (int ks = 0; ks < 2; ++ks) {
            const float* cb = conv_b + ks * 32 + quad * 8;
            float4 a0 = *(const float4*)(ag + ks * 32 + quad * 8);
            float4 a1 = *(const float4*)(ag + ks * 32 + quad * 8 + 4);
            acc[ks][0] = a0.x + cb[0]; acc[ks][1] = a0.y + cb[1];
            acc[ks][2] = a0.z + cb[2]; acc[ks][3] = a0.w + cb[3];
            acc[ks][4] = a1.x + cb[4]; acc[ks][5] = a1.y + cb[5];
            acc[ks][6] = a1.z + cb[6]; acc[ks][7] = a1.w + cb[7];
        }
        int rs = ok ? roff[node] : 0;
        int re = ok ? roff[node + 1] : 0;
        if (re > rs) {
            int b0 = rs >> 6, b1 = (re - 1) >> 6;
            for (int bb = b0 + 1; bb <= b1; ++bb) {
                const float* bp = bpart + (size_t)bb * 64;
#pragma unroll
                for (int ks = 0; ks < 2; ++ks) {
                    float4 p0 = *(const float4*)(bp + ks * 32 + quad * 8);
                    float4 p1 = *(const float4*)(bp + ks * 32 + quad * 8 + 4);
                    acc[ks][0] += p0.x; acc[ks][1] += p0.y;
                    acc[ks][2] += p0.z; acc[ks][3] += p0.w;
                    acc[ks][4] += p1.x; acc[ks][5] += p1.y;
                    acc[ks][6] += p1.z; acc[ks][7] += p1.w;
                }
            }
        }
        const short* hp = &hsS[row * 132];
#pragma unroll
        for (int ks = 0; ks < 2; ++ks) {
            Hh[mt][ks] = *(const short8*)(hp + ks * 32);
            Hl[mt][ks] = *(const short8*)(hp + 64 + ks * 32);
#pragma unroll
            for (int j = 0; j < 8; ++j) {
                float g = ok ? fmaxf(acc[ks][j], 0.0f) : 0.0f;
                short gb = f2bf(g);
                Gh[mt][ks][j] = gb;
                Gl[mt][ks][j] = f2bf(g - bf2f(gb));
            }
        }
    }
    __syncthreads();   // all aggS reads complete before it is reused as output

    const short8* FI = (const short8*)fI;
    const short8* FH = (const short8*)fH;
    floatx4 aI[2][3] = {}, aH[2][3] = {};
#pragma unroll
    for (int ks = 0; ks < 2; ++ks) {
        short8 bIh[3], bIl[3], bHh[3], bHl[3];
#pragma unroll
        for (int g = 0; g < 3; ++g) {
            int t = ks * 12 + g * 4 + nt;   // NT16 = 12 (Nout=192)
            bIh[g] = FI[(t * 2 + 0) * 64 + lane];
            bIl[g] = FI[(t * 2 + 1) * 64 + lane];
            bHh[g] = FH[(t * 2 + 0) * 64 + lane];
            bHl[g] = FH[(t * 2 + 1) * 64 + lane];
        }
#pragma unroll
        for (int mt = 0; mt < 2; ++mt) {
#pragma unroll
            for (int g = 0; g < 3; ++g) {
                aI[mt][g] = __builtin_amdgcn_mfma_f32_16x16x32_bf16(Gh[mt][ks], bIh[g], aI[mt][g], 0, 0, 0);
                aI[mt][g] = __builtin_amdgcn_mfma_f32_16x16x32_bf16(Gl[mt][ks], bIh[g], aI[mt][g], 0, 0, 0);
                aI[mt][g] = __builtin_amdgcn_mfma_f32_16x16x32_bf16(Gh[mt][ks], bIl[g], aI[mt][g], 0, 0, 0);
                aH[mt][g] = __builtin_amdgcn_mfma_f32_16x16x32_bf16(Hh[mt][ks], bHh[g], aH[mt][g], 0, 0, 0);
                aH[mt][g] = __builtin_amdgcn_mfma_f32_16x16x32_bf16(Hl[mt][ks], bHh[g], aH[mt][g], 0, 0, 0);
                aH[mt][g] = __builtin_amdgcn_mfma_f32_16x16x32_bf16(Hh[mt][ks], bHl[g], aH[mt][g], 0, 0, 0);
            }
        }
    }

    int o = nt * 16 + col;
    float br = bih[o], bz = bih[64 + o], bn = bih[128 + o];
    float cr = bhh[o], cz = bhh[64 + o], cn = bhh[128 + o];
#pragma unroll
    for (int mt = 0; mt < 2; ++mt) {
#pragma unroll
        for (int r = 0; r < 4; ++r) {
            int row = mt * 16 + quad * 4 + r;
            float rg = sigf(aI[mt][0][r] + br + aH[mt][0][r] + cr);
            float z  = sigf(aI[mt][1][r] + bz + aH[mt][1][r] + cz);
            float ng = tanhf(aI[mt][2][r] + bn + rg * (aH[mt][2][r] + cn));
            float hold = bf2f(hsS[row * 132 + o]) + bf2f(hsS[row * 132 + 64 + o]);
            aggS[row * 65 + o] = (1.0f - z) * ng + z * hold;
        }
    }
    __syncthreads();

    // coalesced writeout: hs (hi|lo short8) + optional hf (float4)
#pragma unroll
    for (int it = 0; it < 2; ++it) {
        int i = tid * 8 + it * 2048;
        int r = i >> 7, c = i & 127;
        int node = n0 + r;
        if (node < N) {
            bool hiP = (c < 64);
            int f0 = hiP ? c : (c - 64);
            short8 v;
#pragma unroll
            for (int j = 0; j < 8; ++j) {
                float hv = aggS[r * 65 + f0 + j];
                short hb = f2bf(hv);
                v[j] = hiP ? hb : f2bf(hv - bf2f(hb));
            }
            *(short8*)(hs + (size_t)node * 128 + c) = v;
        }
    }
    if (hf) {
#pragma unroll
        for (int it = 0; it < 2; ++it) {
            int i = tid * 4 + it * 1024;
            int r = i >> 6, c = i & 63;
            int node = n0 + r;
            if (node < N)
                *(float4*)(hf + (size_t)node * 64 + c) = *(const float4*)&aggS[r * 65 + c];
        }
    }
}

// ---------------- fused Set2Set: 3 iterations, 512 threads (8 waves) ----------------
// One gate per thread for LSTM matvecs (plain transposed weights, coalesced);
// attention uses 8 waves x 4-node unroll. State lives in LDS across iterations.
// x@W / h@U products skipped when provably zero (it==0). Head prep folded at end.
__launch_bounds__(512)
__global__ void k_s2s3(float* __restrict__ q_star,
                       const float* __restrict__ W0T, const float* __restrict__ U0T,
                       const float* __restrict__ b0i, const float* __restrict__ b0h,
                       const float* __restrict__ W1T, const float* __restrict__ U1T,
                       const float* __restrict__ b1i, const float* __restrict__ b1h,
                       const float* __restrict__ hf, const float* __restrict__ x,
                       const int* __restrict__ gs, const int* __restrict__ ge,
                       const float* sp_W, short* fsp, const float* h0_W1, short* fw1,
                       const float* h0_W2, short* fw2, const float* out_W, short* fow) {
    __shared__ float xb[256], h0b[128], c0b[128], h1b[128], c1b[128];
    __shared__ float gb[512], h0n[128], qv[128];
    __shared__ float mrg[8][2][64];
    __shared__ float ml[8][2];
    int g = blockIdx.x, tid = threadIdx.x;
    int lane = tid & 63, grp = tid >> 6;   // 8 waves
    int s0v = gs[g], s1v = ge[g];
    if (tid < 256) xb[tid] = 0.0f;
    if (tid < 128) { h0b[tid] = 0.0f; c0b[tid] = 0.0f; h1b[tid] = 0.0f; c1b[tid] = 0.0f; }
    __syncthreads();

    for (int it = 0; it < 3; ++it) {
        // ---- LSTM layer 0: thread = gate (512 gates) ----
        float g0 = b0i[tid] + b0h[tid];
        if (it > 0) {
#pragma unroll 4
            for (int i = 0; i < 256; ++i) g0 += xb[i] * W0T[i * 512 + tid];
#pragma unroll 4
            for (int i = 0; i < 128; ++i) g0 += h0b[i] * U0T[i * 512 + tid];
        }
        gb[tid] = g0;
        __syncthreads();
        if (tid < 128) {
            float ii = gb[tid], ff = gb[128 + tid], gg = gb[256 + tid], oo = gb[384 + tid];
            float c = sigf(ff) * c0b[tid] + sigf(ii) * tanhf(gg);
            float hn = sigf(oo) * tanhf(c);
            c0b[tid] = c; h0b[tid] = hn; h0n[tid] = hn;
        }
        __syncthreads();
        // ---- LSTM layer 1: thread = gate ----
        float ga = b1i[tid] + b1h[tid];
#pragma unroll 4
        for (int i = 0; i < 128; ++i) ga += h0n[i] * W1T[i * 512 + tid];
        if (it > 0) {
#pragma unroll 4
            for (int i = 0; i < 128; ++i) ga += h1b[i] * U1T[i * 512 + tid];
        }
        gb[tid] = ga;
        __syncthreads();
        if (tid < 128) {
            float ii = gb[tid], ff = gb[128 + tid], gg = gb[256 + tid], oo = gb[384 + tid];
            float c = sigf(ff) * c1b[tid] + sigf(ii) * tanhf(gg);
            float hn = sigf(oo) * tanhf(c);
            c1b[tid] = c; h1b[tid] = hn; qv[tid] = hn;
        }
        __syncthreads();
        // ---- attention with online softmax, 8 waves x 4 nodes per iteration ----
        float qh = qv[lane], qx = qv[64 + lane];
        float mM = -INFINITY, lL = 0.0f, nh = 0.0f, nx = 0.0f;
        for (int n = s0v + grp; n < s1v; n += 32) {
            float hv[4], xv[4], e[4];
#pragma unroll
            for (int j = 0; j < 4; ++j) {
                int nj = n + 8 * j;
                int nc = (nj < s1v) ? nj : n;   // clamp: n itself is always valid
                hv[j] = hf[(size_t)nc * 64 + lane];
                xv[j] = x[(size_t)nc * 64 + lane];
                e[j] = hv[j] * qh + xv[j] * qx;
            }
#pragma unroll
            for (int off = 32; off; off >>= 1) {
#pragma unroll
                for (int j = 0; j < 4; ++j) e[j] += __shfl_xor(e[j], off, 64);
            }
#pragma unroll
            for (int j = 0; j < 4; ++j)
                if (n + 8 * j >= s1v) e[j] = -INFINITY;
            float mb = fmaxf(fmaxf(e[0], e[1]), fmaxf(e[2], e[3]));
            float mn = fmaxf(mM, mb);
            float sc = expf(mM - mn);
            float w0 = expf(e[0] - mn), w1 = expf(e[1] - mn);
            float w2 = expf(e[2] - mn), w3 = expf(e[3] - mn);
            lL = lL * sc + ((w0 + w1) + (w2 + w3));
            nh = nh * sc + ((w0 * hv[0] + w1 * hv[1]) + (w2 * hv[2] + w3 * hv[3]));
            nx = nx * sc + ((w0 * xv[0] + w1 * xv[1]) + (w2 * xv[2] + w3 * xv[3]));
            mM = mn;
        }
        mrg[grp][0][lane] = nh;
        mrg[grp][1][lane] = nx;
        if (lane == 0) { ml[grp][0] = mM; ml[grp][1] = lL; }
        __syncthreads();
        if (tid < 128) {
            int half = tid >> 6, dl = tid & 63;
            float M = -INFINITY;
#pragma unroll
            for (int i = 0; i < 8; ++i) M = fmaxf(M, ml[i][0]);
            float L = 0.0f, NUM = 0.0f;
#pragma unroll
            for (int i = 0; i < 8; ++i) {
                float sc = expf(ml[i][0] - M);
                L += ml[i][1] * sc;
                NUM += mrg[i][half][dl] * sc;
            }
            xb[128 + tid] = (s1v > s0v) ? NUM / L : 0.0f;
            xb[tid] = qv[tid];
        }
        __syncthreads();
    }
    if (tid < 256) q_star[g * 256 + tid] = xb[tid];

    // ---- folded head fragment prep (ef_t region dead after MP loop) ----
    for (int ii2 = tid; ii2 < 336; ii2 += 512) {
        int idx = g * 336 + ii2;
        if (idx < 16384) { d_prepB(sp_W, fsp, 32, 512, 0, 512, 256, idx); continue; }
        idx -= 16384;
        if (idx < 32768) { d_prepB(h0_W1, fw1, 32, 512, 0, 512, 512, idx); continue; }
        idx -= 32768;
        if (idx < 32768) { d_prepB(h0_W2, fw2, 32, 512, 0, 512, 512, idx); continue; }
        idx -= 32768;
        d_prepB(out_W, fow, 4, 54, 0, 54, 512, idx);
    }
}

// ---------------- head GEMM layer: C = act(A @ W + b), tiled MFMA ----------------
template<int MODE>
__launch_bounds__(256)
__global__ void k_hgemm(const float* __restrict__ A, const short* __restrict__ Bf,
                        const float* __restrict__ bias, const float* __restrict__ pa,
                        float* __restrict__ Cout, int K, int NT16) {
    int tid = threadIdx.x, lane = tid & 63, nt = tid >> 6;
    int quad = lane >> 4, col = lane & 15;
    int s0 = blockIdx.x * 16;
    int ntile = blockIdx.y * 4 + nt;
    int NoutTot = NT16 * 16;
    const short8* F = (const short8*)Bf;
    floatx4 T = {0.0f, 0.0f, 0.0f, 0.0f};
    const float* ap = A + (size_t)(s0 + col) * K + quad * 8;
    int KT = K >> 5;
#pragma unroll 4
    for (int kt = 0; kt < KT; ++kt) {
        short8 ah, al;
        cvt8(ap + kt * 32, ah, al);
        int t = kt * NT16 + ntile;
        short8 bh = F[(t * 2 + 0) * 64 + lane];
        short8 bl = F[(t * 2 + 1) * 64 + lane];
        T = __builtin_amdgcn_mfma_f32_16x16x32_bf16(ah, bh, T, 0, 0, 0);
        T = __builtin_amdgcn_mfma_f32_16x16x32_bf16(al, bh, T, 0, 0, 0);
        T = __builtin_amdgcn_mfma_f32_16x16x32_bf16(ah, bl, T, 0, 0, 0);
    }
    int o = ntile * 16 + col;
    float b = bias[o];
    float a = (MODE == 0) ? pa[0] : 0.0f;
#pragma unroll
    for (int r = 0; r < 4; ++r) {
        float v = T[r] + b;
        if (MODE == 0) v = (v >= 0.0f) ? v : a * v;
        if (MODE == 1) v = fmaxf(v, 0.0f);
        if (MODE == 2) v = tanhf(v);
        Cout[(size_t)(s0 + quad * 4 + r) * NoutTot + o] = v;
    }
}

// ---------------- head output layer + softmax ----------------
__launch_bounds__(256)
__global__ void k_hout(const float* __restrict__ A, const short* __restrict__ Bf,
                       const float* __restrict__ ob, float* __restrict__ out) {
    __shared__ float sm[16][64];
    __shared__ float smax[16], sinv[16];
    int tid = threadIdx.x, lane = tid & 63, nt = tid >> 6;
    int quad = lane >> 4, col = lane & 15;
    int s0 = blockIdx.x * 16;
    const short8* F = (const short8*)Bf;
    floatx4 T = {0.0f, 0.0f, 0.0f, 0.0f};
    const float* ap = A + (size_t)(s0 + col) * 512 + quad * 8;
#pragma unroll 4
    for (int kt = 0; kt < 16; ++kt) {
        short8 ah, al;
        cvt8(ap + kt * 32, ah, al);
        int t = kt * 4 + nt;
        short8 bh = F[(t * 2 + 0) * 64 + lane];
        short8 bl = F[(t * 2 + 1) * 64 + lane];
        T = __builtin_amdgcn_mfma_f32_16x16x32_bf16(ah, bh, T, 0, 0, 0);
        T = __builtin_amdgcn_mfma_f32_16x16x32_bf16(al, bh, T, 0, 0, 0);
        T = __builtin_amdgcn_mfma_f32_16x16x32_bf16(ah, bl, T, 0, 0, 0);
    }
    int o = nt * 16 + col;
    float b = (o < 54) ? ob[o] : 0.0f;
#pragma unroll
    for (int r = 0; r < 4; ++r)
        sm[quad * 4 + r][o] = (o < 54) ? (T[r] + b) : -1e30f;
    __syncthreads();
    if (tid < 16) {
        float m = -INFINITY;
        for (int j = 0; j < 54; ++j) m = fmaxf(m, sm[tid][j]);
        float s = 0.0f;
        for (int j = 0; j < 54; ++j) s += expf(sm[tid][j] - m);
        smax[tid] = m;
        sinv[tid] = 1.0f / s;
    }
    __syncthreads();
    for (int idx = tid; idx < 16 * 54; idx += 256) {
        int srow = idx / 54, oo = idx % 54;
        out[(size_t)(s0 + srow) * 54 + oo] = expf(sm[srow][oo] - smax[srow]) * sinv[srow];
    }
}

// ---------------- driver ----------------
extern "C" void kernel_launch(void* const* d_in, const int* in_sizes, int n_in,
                              void* d_out, int out_size, void* d_ws, size_t ws_size,
                              hipStream_t stream) {
    const float* node_attr = (const float*)d_in[0];
    const float* edge_attr = (const float*)d_in[1];
    const float* edge_len  = (const float*)d_in[2];
    const int*   src       = (const int*)d_in[3];
    const int*   dst       = (const int*)d_in[4];
    const int*   node_grph = (const int*)d_in[5];
    const float* proj_W    = (const float*)d_in[6];
    const float* proj_b    = (const float*)d_in[7];
    const float* centers   = (const float*)d_in[8];
    const float* beta      = (const float*)d_in[9];
    const float* bond_W    = (const float*)d_in[10];
    const float* bond_b    = (const float*)d_in[11];
    const float* conv_b    = (const float*)d_in[12];
    const float* gru_Wih   = (const float*)d_in[13];
    const float* gru_Whh   = (const float*)d_in[14];
    const float* gru_bih   = (const float*)d_in[15];
    const float* gru_bhh   = (const float*)d_in[16];
    const float* lWih0     = (const float*)d_in[17];
    const float* lWhh0     = (const float*)d_in[18];
    const float* lbih0     = (const float*)d_in[19];
    const float* lbhh0     = (const float*)d_in[20];
    const float* lWih1     = (const float*)d_in[21];
    const float* lWhh1     = (const float*)d_in[22];
    const float* lbih1     = (const float*)d_in[23];
    const float* lbhh1     = (const float*)d_in[24];
    const float* sp_W      = (const float*)d_in[25];
    const float* sp_b      = (const float*)d_in[26];
    const float* prelu_a   = (const float*)d_in[27];
    const float* h0_W1     = (const float*)d_in[28];
    const float* h0_b1     = (const float*)d_in[29];
    const float* h0_W2     = (const float*)d_in[30];
    const float* h0_b2     = (const float*)d_in[31];
    const float* out_W     = (const float*)d_in[32];
    const float* out_b     = (const float*)d_in[33];
    float* out = (float*)d_out;

    float* ws = (float*)d_ws;
    size_t off = 0;
    float* x      = ws + off; off += (size_t)N * 64;
    float* hsf    = ws + off; off += (size_t)N * 64;   // N x 128 shorts (hi|lo per node)
    float* ef_t   = ws + off; off += (size_t)E * 17;   // reused by head after MP loop
    float* agg    = ws + off; off += (size_t)N * 64;   // per-node aggregated messages; hf after last step
    float* wfrag  = ws + off; off += 17 * 16 * 64 * 8 / 2;
    float* fgI    = ws + off; off += 2 * 64 * 192 / 2;
    float* fgH    = ws + off; off += 2 * 64 * 192 / 2;
    float* fproj  = ws + off; off += 16 * 1024 / 2;
    float* lW0T   = ws + off; off += 256 * 512;
    float* lU0T   = ws + off; off += 128 * 512;
    float* lW1T   = ws + off; off += 128 * 512;
    float* lU1T   = ws + off; off += 128 * 512;
    float* q_star = ws + off; off += B * 256;
    float* bpart  = ws + off; off += (size_t)NBLK * 64;
    int* gs       = (int*)(ws + off); off += B;
    int* ge       = (int*)(ws + off); off += B;
    int* deg      = (int*)(ws + off); off += N;
    int* cursor   = (int*)(ws + off); off += N;
    int* roff     = (int*)(ws + off); off += N + 1;
    int* bsum     = (int*)(ws + off); off += 256;
    int* srcp     = (int*)(ws + off); off += E;
    int* epos     = (int*)(ws + off); off += E;
    int* dstp     = (int*)(ws + off); off += E;

    short* hs = (short*)hsf;

    // head fragment buffers alias the ef_t region (dead after the MP loop)
    short* fsp = (short*)ef_t;
    short* fw1 = (short*)(ef_t + 131072);
    short* fw2 = (short*)(ef_t + 131072 + 262144);
    short* fow = (short*)(ef_t + 131072 + 2 * 262144);
    float* hb1 = ef_t + 131072 + 2 * 262144 + 32768;
    float* hb2 = hb1 + 131072;

    constexpr int NB = (N + 255) / 256;   // 196

    // ---- one-time: counting sort of edges by dst + CSR offsets ----
    k_izero<<<NB, 256, 0, stream>>>(deg, N);
    k_deg<<<(E + 255) / 256, 256, 0, stream>>>(dst, deg);
    k_scan1<<<NB, 256, 0, stream>>>(deg, bsum);
    k_scan2p<<<1, 256, 0, stream>>>(bsum, NB);
    k_scan3<<<NB, 256, 0, stream>>>(deg, bsum, cursor, roff);
    k_scat<<<(E + 255) / 256, 256, 0, stream>>>(src, dst, cursor, srcp, epos, dstp);

    // fused prep: LSTM transposes + bond/gru/proj fragments + edge feats + bounds
    k_prep0<<<(PREP0_TOTAL + 255) / 256, 256, 0, stream>>>(
        lWih0, lWhh0, lWih1, lWhh1, lW0T, lU0T, lW1T, lU1T,
        bond_W, bond_b, (short*)wfrag, gru_Wih, gru_Whh, (short*)fgI, (short*)fgH,
        proj_W, (short*)fproj,
        edge_attr, edge_len, centers, beta, epos, ef_t,
        node_grph, gs, ge);

    k_projm<<<N / 16, 256, 0, stream>>>(node_attr, (const short*)fproj, proj_b, x, hs);

    for (int step = 0; step < 4; ++step) {
        k_msgagg<<<NBLK, 256, 0, stream>>>(hs, ef_t, (const short*)wfrag, srcp, dstp,
                                           agg, bpart);
        k_gru4<<<(N + 31) / 32, 256, 0, stream>>>(agg, bpart, roff, conv_b, hs,
                                                  (const short*)fgI, (const short*)fgH,
                                                  gru_bih, gru_bhh,
                                                  (step == 3) ? agg : nullptr);
    }

    // fused Set2Set (3 iterations, 512 threads, state in LDS) + head fragment prep folded
    k_s2s3<<<B, 512, 0, stream>>>(q_star,
                                  lW0T, lU0T, lbih0, lbhh0,
                                  lW1T, lU1T, lbih1, lbhh1,
                                  agg, x, gs, ge,
                                  sp_W, fsp, h0_W1, fw1, h0_W2, fw2, out_W, fow);

    // head: 3 MFMA GEMM layers + fused output/softmax (128-block grids)
    k_hgemm<0><<<dim3(16, 8), 256, 0, stream>>>(q_star, fsp, sp_b, prelu_a, hb1, 256, 32);
    k_hgemm<1><<<dim3(16, 8), 256, 0, stream>>>(hb1, fw1, h0_b1, nullptr, hb2, 512, 32);
    k_hgemm<2><<<dim3(16, 8), 256, 0, stream>>>(hb2, fw2, h0_b2, nullptr, hb1, 512, 32);
    k_hout<<<16, 256, 0, stream>>>(hb1, fow, out_b, out);
}

// Round 10
// 662.666 us; speedup vs baseline: 1.0823x; 1.0823x over previous
//
#include <hip/hip_runtime.h>
#include <math.h>

constexpr int N = 50000;     // nodes
constexpr int E = 100000;    // edges
constexpr int B = 256;       // graphs
constexpr int H = 64;
constexpr int DN = 110;
constexpr int NBLK = (E + 63) / 64;   // 1563 message blocks (exact 64-edge blocks)

#define DEV __device__ __forceinline__

typedef __attribute__((ext_vector_type(8))) short short8;
typedef __attribute__((ext_vector_type(4))) float floatx4;

DEV float sigf(float x) { return 1.0f / (1.0f + expf(-x)); }

// bf16 round-to-nearest-even conversion (manual, header-type-free)
DEV short f2bf(float f) {
    unsigned u = __float_as_uint(f);
    unsigned r = (u + 0x7fffu + ((u >> 16) & 1u)) >> 16;
    return (short)r;
}
DEV float bf2f(short s) { return __uint_as_float(((unsigned)(unsigned short)s) << 16); }

// convert 8 contiguous floats -> hi/lo bf16 fragments
DEV void cvt8(const float* p, short8& hi, short8& lo) {
    float4 u0 = *(const float4*)p;
    float4 u1 = *(const float4*)(p + 4);
    float vv[8] = {u0.x, u0.y, u0.z, u0.w, u1.x, u1.y, u1.z, u1.w};
#pragma unroll
    for (int j = 0; j < 8; ++j) {
        short hb = f2bf(vv[j]);
        hi[j] = hb;
        lo[j] = f2bf(vv[j] - bf2f(hb));
    }
}

// ---------------- generic helpers ----------------
__global__ void k_izero(int* p, int n) {
    int i = blockIdx.x * 256 + threadIdx.x;
    if (i < n) p[i] = 0;
}

// ---------------- fused prep device helpers ----------------
// pack LSTM weight transpose as float2 gate-pairs: out2[i][j] = (W[j][i], W[j+256][i])
DEV void d_packpair(const float* __restrict__ in, float* __restrict__ out, int IN_I, int idx) {
    int i = idx >> 8;           // input index
    int j = idx & 255;          // gate pair index
    out[2 * idx]     = in[(size_t)j * IN_I + i];
    out[2 * idx + 1] = in[(size_t)(j + 256) * IN_I + i];
}

DEV void d_prepB(const float* __restrict__ W, short* __restrict__ out,
                 int NT16, int ld, int trans, int ocap, int kcap, int idx) {
    int lane = idx & 63;
    int t = idx >> 6;
    int ntile = t % NT16;
    int kt = t / NT16;
    int quad = lane >> 4, col = lane & 15;
    int o = ntile * 16 + col;
    short hi[8], lo[8];
#pragma unroll
    for (int j = 0; j < 8; ++j) {
        int k = kt * 32 + quad * 8 + j;
        float v = 0.0f;
        if (o < ocap && k < kcap) v = trans ? W[(size_t)o * ld + k] : W[(size_t)k * ld + o];
        short hb = f2bf(v);
        hi[j] = hb;
        lo[j] = f2bf(v - bf2f(hb));
    }
    short* dh = out + (((size_t)(t * 2 + 0) * 64 + lane) * 8);
    short* dl = out + (((size_t)(t * 2 + 1) * 64 + lane) * 8);
#pragma unroll
    for (int j = 0; j < 8; ++j) { dh[j] = hi[j]; dl[j] = lo[j]; }
}

DEV void d_prepW(const float* __restrict__ bond_W, const float* __restrict__ bond_b,
                 short* __restrict__ wf, int idx) {
    int lane = idx & 63;
    int t = idx >> 6;            // (kk*4+nt)*2+ks
    int ks = t & 1;
    int nt = (t >> 1) & 3;
    int kk = t >> 3;
    const float* S = (kk < 16) ? (bond_W + kk * 4096) : bond_b;
    int quad = lane >> 4, col = lane & 15;
    short hi[8], lo[8];
#pragma unroll
    for (int j = 0; j < 8; ++j) {
        int i = ks * 32 + quad * 8 + j;
        float v = S[i * 64 + nt * 16 + col];
        short hb = f2bf(v);
        hi[j] = hb;
        lo[j] = f2bf(v - bf2f(hb));
    }
    short* dh = wf + (((size_t)(t * 2 + 0) * 64 + lane) * 8);
    short* dl = wf + (((size_t)(t * 2 + 1) * 64 + lane) * 8);
#pragma unroll
    for (int j = 0; j < 8; ++j) { dh[j] = hi[j]; dl[j] = lo[j]; }
}

// fused start-of-graph prep: 4 LSTM pack-pairs + bond prepW + gru/proj prepB
//                            + edge features + graph bounds
__launch_bounds__(256)
__global__ void k_prep0(const float* lWih0, const float* lWhh0, const float* lWih1, const float* lWhh1,
                        float* lW0P, float* lU0P, float* lW1P, float* lU1P,
                        const float* bond_W, const float* bond_b, short* wf,
                        const float* gru_Wih, const float* gru_Whh, short* fgI, short* fgH,
                        const float* proj_W, short* fproj,
                        const float* ea, const float* el, const float* centers,
                        const float* beta, const int* epos, float* ef_t,
                        const int* ng, int* gs, int* ge) {
    int idx = blockIdx.x * 256 + threadIdx.x;
    if (idx < 65536) { d_packpair(lWih0, lW0P, 256, idx); return; }
    idx -= 65536;
    if (idx < 32768) { d_packpair(lWhh0, lU0P, 128, idx); return; }
    idx -= 32768;
    if (idx < 32768) { d_packpair(lWih1, lW1P, 128, idx); return; }
    idx -= 32768;
    if (idx < 32768) { d_packpair(lWhh1, lU1P, 128, idx); return; }
    idx -= 32768;
    if (idx < 8704) { d_prepW(bond_W, bond_b, wf, idx); return; }
    idx -= 8704;
    if (idx < 1536) { d_prepB(gru_Wih, fgI, 12, 64, 1, 192, 64, idx); return; }
    idx -= 1536;
    if (idx < 1536) { d_prepB(gru_Whh, fgH, 12, 64, 1, 192, 64, idx); return; }
    idx -= 1536;
    if (idx < 1024) { d_prepB(proj_W, fproj, 4, 64, 0, 64, DN, idx); return; }
    idx -= 1024;
    if (idx < E) {   // edge features -> ef_t[kk][pos], dst-sorted
        int e = idx;
        int pos = epos[e];
        float L = el[e];
#pragma unroll
        for (int j = 0; j < 8; ++j) ef_t[(size_t)j * E + pos] = ea[e * 8 + j];
#pragma unroll
        for (int j = 0; j < 8; ++j) {
            float d = L - centers[j];
            ef_t[(size_t)(8 + j) * E + pos] = expf(-beta[j] * d * d);
        }
        ef_t[(size_t)16 * E + pos] = 1.0f;
        return;
    }
    idx -= E;
    if (idx < N) {   // graph bounds from sorted node_graph
        int n = idx;
        int g = ng[n];
        int gp = (n == 0) ? -1 : ng[n - 1];
        if (g != gp) {
            gs[g] = n;
            if (n > 0) ge[gp] = n;
            for (int q = gp + 1; q < g; ++q) { gs[q] = 0; ge[q] = 0; }
        }
        if (n == N - 1) {
            ge[g] = N;
            for (int q = g + 1; q < B; ++q) { gs[q] = 0; ge[q] = 0; }
        }
        return;
    }
}
constexpr int PREP0_TOTAL = 65536 + 3 * 32768 + 8704 + 2 * 1536 + 1024 + E + N;

// ---------------- edge sort by dst (counting sort), one-time ----------------
__global__ void k_deg(const int* __restrict__ dst, int* __restrict__ deg) {
    int e = blockIdx.x * 256 + threadIdx.x;
    if (e < E) atomicAdd(&deg[dst[e]], 1);
}
__global__ void k_scan1(const int* __restrict__ deg, int* __restrict__ bsum) {
    __shared__ int s[256];
    int b = blockIdx.x, tid = threadIdx.x;
    int idx = b * 256 + tid;
    s[tid] = (idx < N) ? deg[idx] : 0;
    __syncthreads();
    for (int st = 128; st > 0; st >>= 1) {
        if (tid < st) s[tid] += s[tid + st];
        __syncthreads();
    }
    if (tid == 0) bsum[b] = s[0];
}
__global__ void k_scan2p(int* __restrict__ bsum, int nb) {
    __shared__ int s[256];
    int tid = threadIdx.x;
    int v = (tid < nb) ? bsum[tid] : 0;
    s[tid] = v;
    __syncthreads();
    for (int off = 1; off < 256; off <<= 1) {
        int t = (tid >= off) ? s[tid - off] : 0;
        __syncthreads();
        s[tid] += t;
        __syncthreads();
    }
    if (tid < nb) bsum[tid] = s[tid] - v;   // exclusive
}
__global__ void k_scan3(const int* __restrict__ deg, const int* __restrict__ bsum,
                        int* __restrict__ cursor, int* __restrict__ roff) {
    __shared__ int s[256];
    int b = blockIdx.x, tid = threadIdx.x;
    int idx = b * 256 + tid;
    int v = (idx < N) ? deg[idx] : 0;
    s[tid] = v;
    __syncthreads();
    for (int off = 1; off < 256; off <<= 1) {
        int t = (tid >= off) ? s[tid - off] : 0;
        __syncthreads();
        s[tid] += t;
        __syncthreads();
    }
    if (idx < N) {
        int start = bsum[b] + s[tid] - v;
        cursor[idx] = start;
        roff[idx] = start;
    }
    if (idx == 0) roff[N] = E;
}
__global__ void k_scat(const int* __restrict__ src, const int* __restrict__ dst,
                       int* __restrict__ cursor, int* __restrict__ srcp,
                       int* __restrict__ epos, int* __restrict__ dstp) {
    int e = blockIdx.x * 256 + threadIdx.x;
    if (e >= E) return;
    int d = dst[e];
    int pos = atomicAdd(&cursor[d], 1);
    srcp[pos] = src[e];
    dstp[pos] = d;
    epos[e] = pos;
}

// ---------------- projection via MFMA: v = relu(na @ W + b); x = v (fp32); hs = split(v) ----------------
__launch_bounds__(256)
__global__ void k_projm(const float* __restrict__ na, const short* __restrict__ fp,
                        const float* __restrict__ b, float* __restrict__ x,
                        short* __restrict__ hs) {
    __shared__ float as[16 * 132];   // 16 rows, K padded 110->128 (stride 132 vs bank conflicts)
    int tid = threadIdx.x, lane = tid & 63, nt = tid >> 6;
    int quad = lane >> 4, col = lane & 15;
    int s0 = blockIdx.x * 16;
    for (int i = tid; i < 16 * DN; i += 256) {
        int r = i / DN, c = i % DN;
        as[r * 132 + c] = na[(size_t)s0 * DN + i];
    }
    for (int i = tid; i < 16 * 22; i += 256) {
        int r = i / 22, c = DN + i % 22;
        as[r * 132 + c] = 0.0f;
    }
    __syncthreads();
    const short8* F = (const short8*)fp;
    floatx4 T = {0.0f, 0.0f, 0.0f, 0.0f};
#pragma unroll
    for (int kt = 0; kt < 4; ++kt) {
        const float* ap = as + col * 132 + kt * 32 + quad * 8;
        short8 ah, al;
#pragma unroll
        for (int j = 0; j < 8; ++j) {
            float v = ap[j];
            short hb = f2bf(v);
            ah[j] = hb;
            al[j] = f2bf(v - bf2f(hb));
        }
        int t = kt * 4 + nt;
        short8 bh = F[(t * 2 + 0) * 64 + lane];
        short8 bl = F[(t * 2 + 1) * 64 + lane];
        T = __builtin_amdgcn_mfma_f32_16x16x32_bf16(ah, bh, T, 0, 0, 0);
        T = __builtin_amdgcn_mfma_f32_16x16x32_bf16(al, bh, T, 0, 0, 0);
        T = __builtin_amdgcn_mfma_f32_16x16x32_bf16(ah, bl, T, 0, 0, 0);
    }
    int o = nt * 16 + col;
    float bo = b[o];
#pragma unroll
    for (int r = 0; r < 4; ++r) {
        int n = s0 + quad * 4 + r;
        float v = fmaxf(T[r] + bo, 0.0f);
        x[(size_t)n * 64 + o] = v;
        short hb = f2bf(v);
        hs[(size_t)n * 128 + o] = hb;
        hs[(size_t)n * 128 + 64 + o] = f2bf(v - bf2f(hb));
    }
}

// ---------------- message GEMM + in-block dst aggregation (round-5 structure) ----------------
__launch_bounds__(256)
__global__ void k_msgagg(const short* __restrict__ hs, const float* __restrict__ ef_t,
                         const short* __restrict__ wf, const int* __restrict__ srcp,
                         const int* __restrict__ dstp,
                         float* __restrict__ agg, float* __restrict__ bpart) {
    __shared__ float efs[17 * 64];   // [kk][e_local]
    __shared__ int srcs[64];
    __shared__ int dsh[64];
    __shared__ int shprev;
    __shared__ float Csh[64][68];    // per-edge messages; stride 68 -> 2-way banks (free)

    int tid = threadIdx.x;
    int e0 = blockIdx.x * 64;
    int lane = tid & 63;
    int nt = tid >> 6;
    int quad = lane >> 4, col = lane & 15;

    if (tid < 64) {
        int eg = e0 + tid;
        srcs[tid] = (eg < E) ? srcp[eg] : 0;
        dsh[tid] = (eg < E) ? dstp[eg] : N;   // sentinel N for padded rows
    }
    if (tid == 0) shprev = (e0 == 0) ? -1 : dstp[e0 - 1];
    for (int i = tid; i < 17 * 64; i += 256) {
        int kk = i >> 6, e = i & 63;
        int eg = e0 + e;
        efs[i] = (eg < E) ? ef_t[(size_t)kk * E + eg] : 0.0f;
    }
    __syncthreads();

    // A fragments: direct pre-split loads (hi at +0..63, lo at +64..127 per node row)
    short8 Ah[4][2], Al[4][2];
#pragma unroll
    for (int mt = 0; mt < 4; ++mt) {
        int s = srcs[mt * 16 + col];
        const short* hp = hs + (size_t)s * 128 + quad * 8;
#pragma unroll
        for (int ks = 0; ks < 2; ++ks) {
            Ah[mt][ks] = *(const short8*)(hp + ks * 32);
            Al[mt][ks] = *(const short8*)(hp + 64 + ks * 32);
        }
    }

    const short8* Wf = (const short8*)wf;
    float C[4][4] = {};

#define LOADB(d0, d1, d2, d3, KK)                      \
    {                                                  \
        int tb_ = ((KK) * 4 + nt) * 2;                 \
        d0 = Wf[((tb_ + 0) * 2 + 0) * 64 + lane];      \
        d1 = Wf[((tb_ + 1) * 2 + 0) * 64 + lane];      \
        d2 = Wf[((tb_ + 0) * 2 + 1) * 64 + lane];      \
        d3 = Wf[((tb_ + 1) * 2 + 1) * 64 + lane];      \
    }

    // 3-deep software pipeline: hold kk, kk+1, kk+2; prefetch kk+3 each iteration
    short8 c0, c1, c2, c3, n0_, n1_, n2_, n3_, q0, q1, q2, q3;
    LOADB(c0, c1, c2, c3, 0);
    LOADB(n0_, n1_, n2_, n3_, 1);
    LOADB(q0, q1, q2, q3, 2);

#pragma unroll 1
    for (int kk = 0; kk < 17; ++kk) {
        int kn = kk + 3;
        if (kn > 16) kn = 16;
        short8 p0, p1, p2, p3;
        LOADB(p0, p1, p2, p3, kn);

#pragma unroll
        for (int mt = 0; mt < 4; ++mt) {
            floatx4 T = {0.0f, 0.0f, 0.0f, 0.0f};
            T = __builtin_amdgcn_mfma_f32_16x16x32_bf16(Ah[mt][0], c0, T, 0, 0, 0);
            T = __builtin_amdgcn_mfma_f32_16x16x32_bf16(Ah[mt][1], c1, T, 0, 0, 0);
            T = __builtin_amdgcn_mfma_f32_16x16x32_bf16(Al[mt][0], c0, T, 0, 0, 0);
            T = __builtin_amdgcn_mfma_f32_16x16x32_bf16(Al[mt][1], c1, T, 0, 0, 0);
            T = __builtin_amdgcn_mfma_f32_16x16x32_bf16(Ah[mt][0], c2, T, 0, 0, 0);
            T = __builtin_amdgcn_mfma_f32_16x16x32_bf16(Ah[mt][1], c3, T, 0, 0, 0);
            float4 ef = *(const float4*)&efs[kk * 64 + mt * 16 + quad * 4];
            C[mt][0] += ef.x * T[0];
            C[mt][1] += ef.y * T[1];
            C[mt][2] += ef.z * T[2];
            C[mt][3] += ef.w * T[3];
        }
        c0 = n0_; c1 = n1_; c2 = n2_; c3 = n3_;
        n0_ = q0; n1_ = q1; n2_ = q2; n3_ = q3;
        q0 = p0; q1 = p1; q2 = p2; q3 = p3;
    }
#undef LOADB

    // messages -> LDS (padded rows have efs==0 -> C==0)
#pragma unroll
    for (int mt = 0; mt < 4; ++mt)
#pragma unroll
        for (int r = 0; r < 4; ++r)
            Csh[mt * 16 + quad * 4 + r][nt * 16 + col] = C[mt][r];
    __syncthreads();

    // segmented reduction walk: lane c handles output column c
    if (tid < 64) {
        int c = tid;
        int prevd = shprev;
        int firstd = dsh[0];
        for (int q = prevd + 1; q < firstd; ++q) agg[(size_t)q * 64 + c] = 0.0f;
        int cur = firstd;
        float acc = 0.0f;
        bool owned = (e0 == 0) || (firstd != prevd);
        bool done = false;
        for (int r = 0; r < 64; ++r) {
            int d = dsh[r];
            if (d != cur) {
                if (owned) agg[(size_t)cur * 64 + c] = acc;
                else bpart[(size_t)blockIdx.x * 64 + c] = acc;
                int dc = (d < N) ? d : N;
                for (int q = cur + 1; q < dc; ++q) agg[(size_t)q * 64 + c] = 0.0f;
                cur = d;
                acc = 0.0f;
                owned = true;
                if (cur >= N) { done = true; break; }
            }
            acc += Csh[r][c];
        }
        if (!done) {
            if (owned) agg[(size_t)cur * 64 + c] = acc;
            else bpart[(size_t)blockIdx.x * 64 + c] = acc;
        }
    }
}

// ---------------- GRU step (dense): LDS-staged coalesced I/O + split-bf16 MFMA ----------------
__launch_bounds__(256)
__global__ void k_gru4(const float* agg, const float* __restrict__ bpart,
                       const int* __restrict__ roff, const float* __restrict__ conv_b,
                       short* __restrict__ hs,
                       const short* __restrict__ fI, const short* __restrict__ fH,
                       const float* __restrict__ bih, const float* __restrict__ bhh,
                       float* hf) {
    __shared__ float aggS[32 * 65];   // staged agg rows; reused as hn output buffer
    __shared__ short hsS[32 * 132];   // staged hs rows (hi|lo), stride 132 vs bank conflicts
    int tid = threadIdx.x, lane = tid & 63, nt = tid >> 6;
    int quad = lane >> 4, col = lane & 15;
    int n0 = blockIdx.x * 32;

    // coalesced stage: agg (32x64 f32 = 8KB) and hs (32x128 shorts = 8KB)
    {
        const float* src = agg + (size_t)n0 * 64;
#pragma unroll
        for (int it = 0; it < 2; ++it) {
            int i = tid * 4 + it * 1024;
            float4 v = {0.0f, 0.0f, 0.0f, 0.0f};
            if ((size_t)n0 * 64 + i + 3 < (size_t)N * 64) v = *(const float4*)(src + i);
            int r = i >> 6, c = i & 63;
            *(float4*)&aggS[r * 65 + c] = v;
        }
        const short* hsrc = hs + (size_t)n0 * 128;
#pragma unroll
        for (int it = 0; it < 2; ++it) {
            int i = tid * 8 + it * 2048;
            short8 v = short8{0, 0, 0, 0, 0, 0, 0, 0};
            if ((size_t)n0 * 128 + i + 7 < (size_t)N * 128) v = *(const short8*)(hsrc + i);
            int r = i >> 7, c = i & 127;
            *(short8*)&hsS[r * 132 + c] = v;
        }
    }
    __syncthreads();

    short8 Gh[2][2], Gl[2][2], Hh[2][2], Hl[2][2];
#pragma unroll
    for (int mt = 0; mt < 2; ++mt) {
        int node = n0 + mt * 16 + col;
        bool ok = node < N;
        int row = mt * 16 + col;
        float acc[2][8];
        const float* ag = &aggS[row * 65];
#pragma unroll
        for (int ks = 0; ks < 2; ++ks) {
            const float* cb = conv_b + ks * 32 + quad * 8;
            float4 a0 = *(const float4*)(ag + ks * 32 + quad * 8);
            float4 a1 = *(const float4*)(ag + ks * 32 + quad * 8 + 4);
            acc[ks][0] = a0.x + cb[0]; acc[ks][1] = a0.y + cb[1];
            acc[ks][2] = a0.z + cb[2]; acc[ks][3] = a0.w + cb[3];
            acc[ks][4] = a1.x + cb[4]; acc[ks][5] = a1.y + cb[5];
            acc[ks][6] = a1.z + cb[6]; acc[ks][7] = a1.w + cb[7];
        }
        int rs = ok ? roff[node] : 0;
        int re = ok ? roff[node + 1] : 0;
        if (re > rs) {
            int b0 = rs >> 6, b1 = (re - 1) >> 6;
            for (int bb = b0 + 1; bb <= b1; ++bb) {
                const float* bp = bpart + (size_t)bb * 64;
#pragma unroll
                for (int ks = 0; ks < 2; ++ks) {
                    float4 p0 = *(const float4*)(bp + ks * 32 + quad * 8);
                    float4 p1 = *(const float4*)(bp + ks * 32 + quad * 8 + 4);
                    acc[ks][0] += p0.x; acc[ks][1] += p0.y;
                    acc[ks][2] += p0.z; acc[ks][3] += p0.w;
                    acc[ks][4] += p1.x; acc[ks][5] += p1.y;
                    acc[ks][6] += p1.z; acc[ks][7] += p1.w;
                }
            }
        }
        const short* hp = &hsS[row * 132];
#pragma unroll
        for (int ks = 0; ks < 2; ++ks) {
            Hh[mt][ks] = *(const short8*)(hp + ks * 32);
            Hl[mt][ks] = *(const short8*)(hp + 64 + ks * 32);
#pragma unroll
            for (int j = 0; j < 8; ++j) {
                float g = ok ? fmaxf(acc[ks][j], 0.0f) : 0.0f;
                short gb = f2bf(g);
                Gh[mt][ks][j] = gb;
                Gl[mt][ks][j] = f2bf(g - bf2f(gb));
            }
        }
    }
    __syncthreads();   // all aggS reads complete before it is reused as output

    const short8* FI = (const short8*)fI;
    const short8* FH = (const short8*)fH;
    floatx4 aI[2][3] = {}, aH[2][3] = {};
#pragma unroll
    for (int ks = 0; ks < 2; ++ks) {
        short8 bIh[3], bIl[3], bHh[3], bHl[3];
#pragma unroll
        for (int g = 0; g < 3; ++g) {
            int t = ks * 12 + g * 4 + nt;   // NT16 = 12 (Nout=192)
            bIh[g] = FI[(t * 2 + 0) * 64 + lane];
            bIl[g] = FI[(t * 2 + 1) * 64 + lane];
            bHh[g] = FH[(t * 2 + 0) * 64 + lane];
            bHl[g] = FH[(t * 2 + 1) * 64 + lane];
        }
#pragma unroll
        for (int mt = 0; mt < 2; ++mt) {
#pragma unroll
            for (int g = 0; g < 3; ++g) {
                aI[mt][g] = __builtin_amdgcn_mfma_f32_16x16x32_bf16(Gh[mt][ks], bIh[g], aI[mt][g], 0, 0, 0);
                aI[mt][g] = __builtin_amdgcn_mfma_f32_16x16x32_bf16(Gl[mt][ks], bIh[g], aI[mt][g], 0, 0, 0);
                aI[mt][g] = __builtin_amdgcn_mfma_f32_16x16x32_bf16(Gh[mt][ks], bIl[g], aI[mt][g], 0, 0, 0);
                aH[mt][g] = __builtin_amdgcn_mfma_f32_16x16x32_bf16(Hh[mt][ks], bHh[g], aH[mt][g], 0, 0, 0);
                aH[mt][g] = __builtin_amdgcn_mfma_f32_16x16x32_bf16(Hl[mt][ks], bHh[g], aH[mt][g], 0, 0, 0);
                aH[mt][g] = __builtin_amdgcn_mfma_f32_16x16x32_bf16(Hh[mt][ks], bHl[g], aH[mt][g], 0, 0, 0);
            }
        }
    }

    int o = nt * 16 + col;
    float br = bih[o], bz = bih[64 + o], bn = bih[128 + o];
    float cr = bhh[o], cz = bhh[64 + o], cn = bhh[128 + o];
#pragma unroll
    for (int mt = 0; mt < 2; ++mt) {
#pragma unroll
        for (int r = 0; r < 4; ++r) {
            int row = mt * 16 + quad * 4 + r;
            float rg = sigf(aI[mt][0][r] + br + aH[mt][0][r] + cr);
            float z  = sigf(aI[mt][1][r] + bz + aH[mt][1][r] + cz);
            float ng = tanhf(aI[mt][2][r] + bn + rg * (aH[mt][2][r] + cn));
            float hold = bf2f(hsS[row * 132 + o]) + bf2f(hsS[row * 132 + 64 + o]);
            aggS[row * 65 + o] = (1.0f - z) * ng + z * hold;
        }
    }
    __syncthreads();

    // coalesced writeout: hs (hi|lo short8) + optional hf (float4)
#pragma unroll
    for (int it = 0; it < 2; ++it) {
        int i = tid * 8 + it * 2048;
        int r = i >> 7, c = i & 127;
        int node = n0 + r;
        if (node < N) {
            bool hiP = (c < 64);
            int f0 = hiP ? c : (c - 64);
            short8 v;
#pragma unroll
            for (int j = 0; j < 8; ++j) {
                float hv = aggS[r * 65 + f0 + j];
                short hb = f2bf(hv);
                v[j] = hiP ? hb : f2bf(hv - bf2f(hb));
            }
            *(short8*)(hs + (size_t)node * 128 + c) = v;
        }
    }
    if (hf) {
#pragma unroll
        for (int it = 0; it < 2; ++it) {
            int i = tid * 4 + it * 1024;
            int r = i >> 6, c = i & 63;
            int node = n0 + r;
            if (node < N)
                *(float4*)(hf + (size_t)node * 64 + c) = *(const float4*)&aggS[r * 65 + c];
        }
    }
}

// ---------------- fused Set2Set: 3 iterations, 256 threads, ILP-widened ----------------
// Pack-pair weights (float2/lane); matvecs use 4 independent accumulator chains +
// unroll 8 for deep load pipelining; attention 8-node unroll per wave. State in LDS.
__launch_bounds__(256)
__global__ void k_s2s3(float* __restrict__ q_star,
                       const float* __restrict__ W0P, const float* __restrict__ U0P,
                       const float* __restrict__ b0i, const float* __restrict__ b0h,
                       const float* __restrict__ W1P, const float* __restrict__ U1P,
                       const float* __restrict__ b1i, const float* __restrict__ b1h,
                       const float* __restrict__ hf, const float* __restrict__ x,
                       const int* __restrict__ gs, const int* __restrict__ ge,
                       const float* sp_W, short* fsp, const float* h0_W1, short* fw1,
                       const float* h0_W2, short* fw2, const float* out_W, short* fow) {
    __shared__ float xb[256], h0b[128], c0b[128], h1b[128], c1b[128];
    __shared__ float gb[512], h0n[128], qv[128];
    __shared__ float mrg[4][2][64];
    __shared__ float ml[4][2];
    int g = blockIdx.x, tid = threadIdx.x;
    int lane = tid & 63, grp = tid >> 6;
    int s0v = gs[g], s1v = ge[g];
    xb[tid] = 0.0f;
    if (tid < 128) { h0b[tid] = 0.0f; c0b[tid] = 0.0f; h1b[tid] = 0.0f; c1b[tid] = 0.0f; }
    __syncthreads();

    for (int it = 0; it < 3; ++it) {
        // ---- LSTM layer 0 (x = xb, h = h0b; both zero on it==0) ----
        float g0 = b0i[tid] + b0h[tid];
        float g1 = b0i[tid + 256] + b0h[tid + 256];
        if (it > 0) {
            float a0 = 0.0f, a1 = 0.0f, b0v = 0.0f, b1v = 0.0f;
#pragma unroll 8
            for (int i = 0; i < 256; i += 2) {
                float xx0 = xb[i], xx1 = xb[i + 1];
                float2 w0 = *(const float2*)(W0P + 2 * (i * 256 + tid));
                float2 w1 = *(const float2*)(W0P + 2 * ((i + 1) * 256 + tid));
                a0 += xx0 * w0.x; a1 += xx0 * w0.y;
                b0v += xx1 * w1.x; b1v += xx1 * w1.y;
            }
#pragma unroll 8
            for (int i = 0; i < 128; i += 2) {
                float hh0 = h0b[i], hh1 = h0b[i + 1];
                float2 w0 = *(const float2*)(U0P + 2 * (i * 256 + tid));
                float2 w1 = *(const float2*)(U0P + 2 * ((i + 1) * 256 + tid));
                a0 += hh0 * w0.x; a1 += hh0 * w0.y;
                b0v += hh1 * w1.x; b1v += hh1 * w1.y;
            }
            g0 += a0 + b0v;
            g1 += a1 + b1v;
        }
        gb[tid] = g0; gb[tid + 256] = g1;
        __syncthreads();
        if (tid < 128) {
            float ii = gb[tid], ff = gb[128 + tid], gg = gb[256 + tid], oo = gb[384 + tid];
            float c = sigf(ff) * c0b[tid] + sigf(ii) * tanhf(gg);
            float hn = sigf(oo) * tanhf(c);
            c0b[tid] = c; h0b[tid] = hn; h0n[tid] = hn;
        }
        __syncthreads();
        // ---- LSTM layer 1 (x = h0n, h = h1b; h1b zero on it==0) ----
        float ga = b1i[tid] + b1h[tid];
        float gbv = b1i[tid + 256] + b1h[tid + 256];
        {
            float a0 = 0.0f, a1 = 0.0f, b0v = 0.0f, b1v = 0.0f;
#pragma unroll 8
            for (int i = 0; i < 128; i += 2) {
                float xx0 = h0n[i], xx1 = h0n[i + 1];
                float2 w0 = *(const float2*)(W1P + 2 * (i * 256 + tid));
                float2 w1 = *(const float2*)(W1P + 2 * ((i + 1) * 256 + tid));
                a0 += xx0 * w0.x; a1 += xx0 * w0.y;
                b0v += xx1 * w1.x; b1v += xx1 * w1.y;
            }
            if (it > 0) {
#pragma unroll 8
                for (int i = 0; i < 128; i += 2) {
                    float hh0 = h1b[i], hh1 = h1b[i + 1];
                    float2 w0 = *(const float2*)(U1P + 2 * (i * 256 + tid));
                    float2 w1 = *(const float2*)(U1P + 2 * ((i + 1) * 256 + tid));
                    a0 += hh0 * w0.x; a1 += hh0 * w0.y;
                    b0v += hh1 * w1.x; b1v += hh1 * w1.y;
                }
            }
            ga += a0 + b0v;
            gbv += a1 + b1v;
        }
        gb[tid] = ga; gb[tid + 256] = gbv;
        __syncthreads();
        if (tid < 128) {
            float ii = gb[tid], ff = gb[128 + tid], gg = gb[256 + tid], oo = gb[384 + tid];
            float c = sigf(ff) * c1b[tid] + sigf(ii) * tanhf(gg);
            float hn = sigf(oo) * tanhf(c);
            c1b[tid] = c; h1b[tid] = hn; qv[tid] = hn;
        }
        __syncthreads();
        // ---- attention with online softmax, 8 nodes per wave per iteration ----
        float qh = qv[lane], qx = qv[64 + lane];
        float mM = -INFINITY, lL = 0.0f, nh = 0.0f, nx = 0.0f;
        for (int n = s0v + grp; n < s1v; n += 32) {
            float hv[8], xv[8], e[8];
#pragma unroll
            for (int j = 0; j < 8; ++j) {
                int nj = n + 4 * j;
                int nc = (nj < s1v) ? nj : n;   // clamp: n itself is always valid
                hv[j] = hf[(size_t)nc * 64 + lane];
                xv[j] = x[(size_t)nc * 64 + lane];
                e[j] = hv[j] * qh + xv[j] * qx;
            }
#pragma unroll
            for (int off = 32; off; off >>= 1) {
#pragma unroll
                for (int j = 0; j < 8; ++j) e[j] += __shfl_xor(e[j], off, 64);
            }
#pragma unroll
            for (int j = 0; j < 8; ++j)
                if (n + 4 * j >= s1v) e[j] = -INFINITY;
            float mb = fmaxf(fmaxf(fmaxf(e[0], e[1]), fmaxf(e[2], e[3])),
                             fmaxf(fmaxf(e[4], e[5]), fmaxf(e[6], e[7])));
            float mn = fmaxf(mM, mb);
            float sc = expf(mM - mn);
            float w[8];
            float ws = 0.0f, wh = 0.0f, wx = 0.0f;
#pragma unroll
            for (int j = 0; j < 8; ++j) {
                w[j] = expf(e[j] - mn);
                ws += w[j];
                wh += w[j] * hv[j];
                wx += w[j] * xv[j];
            }
            lL = lL * sc + ws;
            nh = nh * sc + wh;
            nx = nx * sc + wx;
            mM = mn;
        }
        mrg[grp][0][lane] = nh;
        mrg[grp][1][lane] = nx;
        if (lane == 0) { ml[grp][0] = mM; ml[grp][1] = lL; }
        __syncthreads();
        if (tid < 128) {
            int half = tid >> 6, dl = tid & 63;
            float M = -INFINITY;
#pragma unroll
            for (int i = 0; i < 4; ++i) M = fmaxf(M, ml[i][0]);
            float L = 0.0f, NUM = 0.0f;
#pragma unroll
            for (int i = 0; i < 4; ++i) {
                float sc = expf(ml[i][0] - M);
                L += ml[i][1] * sc;
                NUM += mrg[i][half][dl] * sc;
            }
            xb[128 + tid] = (s1v > s0v) ? NUM / L : 0.0f;
            xb[tid] = qv[tid];
        }
        __syncthreads();
    }
    q_star[g * 256 + tid] = xb[tid];

    // ---- folded head fragment prep (ef_t region dead after MP loop) ----
    for (int ii2 = tid; ii2 < 336; ii2 += 256) {
        int idx = g * 336 + ii2;
        if (idx < 16384) { d_prepB(sp_W, fsp, 32, 512, 0, 512, 256, idx); continue; }
        idx -= 16384;
        if (idx < 32768) { d_prepB(h0_W1, fw1, 32, 512, 0, 512, 512, idx); continue; }
        idx -= 32768;
        if (idx < 32768) { d_prepB(h0_W2, fw2, 32, 512, 0, 512, 512, idx); continue; }
        idx -= 32768;
        d_prepB(out_W, fow, 4, 54, 0, 54, 512, idx);
    }
}

// ---------------- head GEMM layer: C = act(A @ W + b), tiled MFMA ----------------
template<int MODE>
__launch_bounds__(256)
__global__ void k_hgemm(const float* __restrict__ A, const short* __restrict__ Bf,
                        const float* __restrict__ bias, const float* __restrict__ pa,
                        float* __restrict__ Cout, int K, int NT16) {
    int tid = threadIdx.x, lane = tid & 63, nt = tid >> 6;
    int quad = lane >> 4, col = lane & 15;
    int s0 = blockIdx.x * 16;
    int ntile = blockIdx.y * 4 + nt;
    int NoutTot = NT16 * 16;
    const short8* F = (const short8*)Bf;
    floatx4 T = {0.0f, 0.0f, 0.0f, 0.0f};
    const float* ap = A + (size_t)(s0 + col) * K + quad * 8;
    int KT = K >> 5;
#pragma unroll 4
    for (int kt = 0; kt < KT; ++kt) {
        short8 ah, al;
        cvt8(ap + kt * 32, ah, al);
        int t = kt * NT16 + ntile;
        short8 bh = F[(t * 2 + 0) * 64 + lane];
        short8 bl = F[(t * 2 + 1) * 64 + lane];
        T = __builtin_amdgcn_mfma_f32_16x16x32_bf16(ah, bh, T, 0, 0, 0);
        T = __builtin_amdgcn_mfma_f32_16x16x32_bf16(al, bh, T, 0, 0, 0);
        T = __builtin_amdgcn_mfma_f32_16x16x32_bf16(ah, bl, T, 0, 0, 0);
    }
    int o = ntile * 16 + col;
    float b = bias[o];
    float a = (MODE == 0) ? pa[0] : 0.0f;
#pragma unroll
    for (int r = 0; r < 4; ++r) {
        float v = T[r] + b;
        if (MODE == 0) v = (v >= 0.0f) ? v : a * v;
        if (MODE == 1) v = fmaxf(v, 0.0f);
        if (MODE == 2) v = tanhf(v);
        Cout[(size_t)(s0 + quad * 4 + r) * NoutTot + o] = v;
    }
}

// ---------------- head output layer + softmax ----------------
__launch_bounds__(256)
__global__ void k_hout(const float* __restrict__ A, const short* __restrict__ Bf,
                       const float* __restrict__ ob, float* __restrict__ out) {
    __shared__ float sm[16][64];
    __shared__ float smax[16], sinv[16];
    int tid = threadIdx.x, lane = tid & 63, nt = tid >> 6;
    int quad = lane >> 4, col = lane & 15;
    int s0 = blockIdx.x * 16;
    const short8* F = (const short8*)Bf;
    floatx4 T = {0.0f, 0.0f, 0.0f, 0.0f};
    const float* ap = A + (size_t)(s0 + col) * 512 + quad * 8;
#pragma unroll 4
    for (int kt = 0; kt < 16; ++kt) {
        short8 ah, al;
        cvt8(ap + kt * 32, ah, al);
        int t = kt * 4 + nt;
        short8 bh = F[(t * 2 + 0) * 64 + lane];
        short8 bl = F[(t * 2 + 1) * 64 + lane];
        T = __builtin_amdgcn_mfma_f32_16x16x32_bf16(ah, bh, T, 0, 0, 0);
        T = __builtin_amdgcn_mfma_f32_16x16x32_bf16(al, bh, T, 0, 0, 0);
        T = __builtin_amdgcn_mfma_f32_16x16x32_bf16(ah, bl, T, 0, 0, 0);
    }
    int o = nt * 16 + col;
    float b = (o < 54) ? ob[o] : 0.0f;
#pragma unroll
    for (int r = 0; r < 4; ++r)
        sm[quad * 4 + r][o] = (o < 54) ? (T[r] + b) : -1e30f;
    __syncthreads();
    if (tid < 16) {
        float m = -INFINITY;
        for (int j = 0; j < 54; ++j) m = fmaxf(m, sm[tid][j]);
        float s = 0.0f;
        for (int j = 0; j < 54; ++j) s += expf(sm[tid][j] - m);
        smax[tid] = m;
        sinv[tid] = 1.0f / s;
    }
    __syncthreads();
    for (int idx = tid; idx < 16 * 54; idx += 256) {
        int srow = idx / 54, oo = idx % 54;
        out[(size_t)(s0 + srow) * 54 + oo] = expf(sm[srow][oo] - smax[srow]) * sinv[srow];
    }
}

// ---------------- driver ----------------
extern "C" void kernel_launch(void* const* d_in, const int* in_sizes, int n_in,
                              void* d_out, int out_size, void* d_ws, size_t ws_size,
                              hipStream_t stream) {
    const float* node_attr = (const float*)d_in[0];
    const float* edge_attr = (const float*)d_in[1];
    const float* edge_len  = (const float*)d_in[2];
    const int*   src       = (const int*)d_in[3];
    const int*   dst       = (const int*)d_in[4];
    const int*   node_grph = (const int*)d_in[5];
    const float* proj_W    = (const float*)d_in[6];
    const float* proj_b    = (const float*)d_in[7];
    const float* centers   = (const float*)d_in[8];
    const float* beta      = (const float*)d_in[9];
    const float* bond_W    = (const float*)d_in[10];
    const float* bond_b    = (const float*)d_in[11];
    const float* conv_b    = (const float*)d_in[12];
    const float* gru_Wih   = (const float*)d_in[13];
    const float* gru_Whh   = (const float*)d_in[14];
    const float* gru_bih   = (const float*)d_in[15];
    const float* gru_bhh   = (const float*)d_in[16];
    const float* lWih0     = (const float*)d_in[17];
    const float* lWhh0     = (const float*)d_in[18];
    const float* lbih0     = (const float*)d_in[19];
    const float* lbhh0     = (const float*)d_in[20];
    const float* lWih1     = (const float*)d_in[21];
    const float* lWhh1     = (const float*)d_in[22];
    const float* lbih1     = (const float*)d_in[23];
    const float* lbhh1     = (const float*)d_in[24];
    const float* sp_W      = (const float*)d_in[25];
    const float* sp_b      = (const float*)d_in[26];
    const float* prelu_a   = (const float*)d_in[27];
    const float* h0_W1     = (const float*)d_in[28];
    const float* h0_b1     = (const float*)d_in[29];
    const float* h0_W2     = (const float*)d_in[30];
    const float* h0_b2     = (const float*)d_in[31];
    const float* out_W     = (const float*)d_in[32];
    const float* out_b     = (const float*)d_in[33];
    float* out = (float*)d_out;

    float* ws = (float*)d_ws;
    size_t off = 0;
    float* x      = ws + off; off += (size_t)N * 64;
    float* hsf    = ws + off; off += (size_t)N * 64;   // N x 128 shorts (hi|lo per node)
    float* ef_t   = ws + off; off += (size_t)E * 17;   // reused by head after MP loop
    float* agg    = ws + off; off += (size_t)N * 64;   // per-node aggregated messages; hf after last step
    float* wfrag  = ws + off; off += 17 * 16 * 64 * 8 / 2;
    float* fgI    = ws + off; off += 2 * 64 * 192 / 2;
    float* fgH    = ws + off; off += 2 * 64 * 192 / 2;
    float* fproj  = ws + off; off += 16 * 1024 / 2;
    float* lW0P   = ws + off; off += 256 * 512;        // packed float2 gate-pairs
    float* lU0P   = ws + off; off += 128 * 512;
    float* lW1P   = ws + off; off += 128 * 512;
    float* lU1P   = ws + off; off += 128 * 512;
    float* q_star = ws + off; off += B * 256;
    float* bpart  = ws + off; off += (size_t)NBLK * 64;
    int* gs       = (int*)(ws + off); off += B;
    int* ge       = (int*)(ws + off); off += B;
    int* deg      = (int*)(ws + off); off += N;
    int* cursor   = (int*)(ws + off); off += N;
    int* roff     = (int*)(ws + off); off += N + 1;
    int* bsum     = (int*)(ws + off); off += 256;
    int* srcp     = (int*)(ws + off); off += E;
    int* epos     = (int*)(ws + off); off += E;
    int* dstp     = (int*)(ws + off); off += E;

    short* hs = (short*)hsf;

    // head fragment buffers alias the ef_t region (dead after the MP loop)
    short* fsp = (short*)ef_t;
    short* fw1 = (short*)(ef_t + 131072);
    short* fw2 = (short*)(ef_t + 131072 + 262144);
    short* fow = (short*)(ef_t + 131072 + 2 * 262144);
    float* hb1 = ef_t + 131072 + 2 * 262144 + 32768;
    float* hb2 = hb1 + 131072;

    constexpr int NB = (N + 255) / 256;   // 196

    // ---- one-time: counting sort of edges by dst + CSR offsets ----
    k_izero<<<NB, 256, 0, stream>>>(deg, N);
    k_deg<<<(E + 255) / 256, 256, 0, stream>>>(dst, deg);
    k_scan1<<<NB, 256, 0, stream>>>(deg, bsum);
    k_scan2p<<<1, 256, 0, stream>>>(bsum, NB);
    k_scan3<<<NB, 256, 0, stream>>>(deg, bsum, cursor, roff);
    k_scat<<<(E + 255) / 256, 256, 0, stream>>>(src, dst, cursor, srcp, epos, dstp);

    // fused prep: LSTM pack-pairs + bond/gru/proj fragments + edge feats + bounds
    k_prep0<<<(PREP0_TOTAL + 255) / 256, 256, 0, stream>>>(
        lWih0, lWhh0, lWih1, lWhh1, lW0P, lU0P, lW1P, lU1P,
        bond_W, bond_b, (short*)wfrag, gru_Wih, gru_Whh, (short*)fgI, (short*)fgH,
        proj_W, (short*)fproj,
        edge_attr, edge_len, centers, beta, epos, ef_t,
        node_grph, gs, ge);

    k_projm<<<N / 16, 256, 0, stream>>>(node_attr, (const short*)fproj, proj_b, x, hs);

    for (int step = 0; step < 4; ++step) {
        k_msgagg<<<NBLK, 256, 0, stream>>>(hs, ef_t, (const short*)wfrag, srcp, dstp,
                                           agg, bpart);
        k_gru4<<<(N + 31) / 32, 256, 0, stream>>>(agg, bpart, roff, conv_b, hs,
                                                  (const short*)fgI, (const short*)fgH,
                                                  gru_bih, gru_bhh,
                                                  (step == 3) ? agg : nullptr);
    }

    // fused Set2Set (3 iterations, state in LDS) + head fragment prep folded
    k_s2s3<<<B, 256, 0, stream>>>(q_star,
                                  lW0P, lU0P, lbih0, lbhh0,
                                  lW1P, lU1P, lbih1, lbhh1,
                                  agg, x, gs, ge,
                                  sp_W, fsp, h0_W1, fw1, h0_W2, fw2, out_W, fow);

    // head: 3 MFMA GEMM layers + fused output/softmax (128-block grids)
    k_hgemm<0><<<dim3(16, 8), 256, 0, stream>>>(q_star, fsp, sp_b, prelu_a, hb1, 256, 32);
    k_hgemm<1><<<dim3(16, 8), 256, 0, stream>>>(hb1, fw1, h0_b1, nullptr, hb2, 512, 32);
    k_hgemm<2><<<dim3(16, 8), 256, 0, stream>>>(hb2, fw2, h0_b2, nullptr, hb1, 512, 32);
    k_hout<<<16, 256, 0, stream>>>(hb1, fow, out_b, out);
}